// Round 9
// baseline (93.523 us; speedup 1.0000x reference)
//
#include <hip/hip_runtime.h>

// IDW, POWER=2.0 -> w = 1/d2 (sqrt cancels). out = sum(w*v)/sum(w).
// B=2, P=131072, S=512.
// R14: overhead model fixed (dur = 40us fill + kernel + 12.4us graph):
//   duty by round: R11(GPT8,1w/SIMD)=64%, R13(GPT8,2w/SIMD)=53%,
//   R12/R10/R6 ~ 48-52%. Duty FELL 1->2 waves in the same structure =>
//   shared-resource collision, not hideable latency. Only shared unit in
//   the loop: LDS. R11 residual = ~313 cyc/chunk stall => broadcast
//   ds_read_b128 is far costlier than the 12-cyc model and contends across
//   waves. Instruction mix is optimal (R9: rcp ~ 5 issue-cyc; 8-way
//   combine algebra nets 0).
//   This round: remove the LDS unit from the loop entirely -- SMEM at
//   GPT=8. R8's SMEM failure was SGPR starvation at GPT=1 (96 SGPR/group);
//   at GPT=8 a chunk = 12 SGPRs per 536 compute-cyc -> 4+ chunks pipeline
//   in ~90 free SGPRs. __launch_bounds__(256,1) unlocks VGPRs (R11 showed
//   compiler self-capped at 56). Full chip via NSPLIT=2 station split
//   (256 blocks = exactly 1 wave/SIMD; split already verified by R13).
//   Issue floor: 64 chunks x 8 quads x 67cyc = 14.3us @100% duty.
//   Pre-committed: duty>=80% -> total ~73-76; ~64% -> ~80 (declare
//   intrinsic); <50% -> SMEM pipelining failed, LDS is final.
// Math unchanged since R6: 4-way rcp-combine, 31 VALU + 1 trans per quad;
//   EPS2 folded into the d2 fma chain (exact at d2==0: w -> 1/EPS^2).
//   dx = sx - gx (squared anyway; SGPR rides src0, <=1 SGPR per VALU op).

#define BLOCK 256
#define GPT 8
#define NSPLIT 2
#define S_TOT 512
#define S_SUB (S_TOT / NSPLIT)  // 256 stations per block

__device__ __forceinline__ void quad_sm(float gx, float gy, float& ws, float& vs,
                                        const float4& c0, const float4& c1,
                                        const float4& vv) {
    constexpr float EPS  = 1.1920928955078125e-07f;
    constexpr float EPS2 = EPS * EPS;
    // c0 = {Ax,Ay,Bx,By}, c1 = {Cx,Cy,Dx,Dy}, vv = {vA,vB,vC,vD} (SGPRs).
    const float dxa = c0.x - gx, dya = c0.y - gy;
    const float a = fmaf(dxa, dxa, fmaf(dya, dya, EPS2));
    const float dxb = c0.z - gx, dyb = c0.w - gy;
    const float bq = fmaf(dxb, dxb, fmaf(dyb, dyb, EPS2));
    const float dxc = c1.x - gx, dyc = c1.y - gy;
    const float c = fmaf(dxc, dxc, fmaf(dyc, dyc, EPS2));
    const float dxd = c1.z - gx, dyd = c1.w - gy;
    const float d = fmaf(dxd, dxd, fmaf(dyd, dyd, EPS2));
    const float pab = a * bq, pcd = c * d;
    const float sab = a + bq, scd = c + d;
    const float nab = fmaf(vv.y, a, vv.x * bq);  // vB*a + vA*b
    const float ncd = fmaf(vv.w, c, vv.z * d);   // vD*c + vC*d
    const float r = __builtin_amdgcn_rcpf(pab * pcd);
    ws = fmaf(fmaf(sab, pcd, scd * pab), r, ws);
    vs = fmaf(fmaf(nab, pcd, ncd * pab), r, vs);
}

// Main: block = (point-tile x, batch y, station-half z). SMEM stations.
__global__ __launch_bounds__(BLOCK, 1) void idw_main(
    const float* __restrict__ station_coords,  // (B, S, 2)
    const float* __restrict__ station_values,  // (B, S)
    const float* __restrict__ grid_points,     // (B, P, 2)
    float2* __restrict__ partial,              // (NSPLIT, B, P) float2
    int P, int S) {

    const int b = blockIdx.y;
    const int z = blockIdx.z;

    // Wave-uniform station pointers -> s_load into SGPRs (K$-resident 3KB).
    const float4* __restrict__ sc4 =
        (const float4*)station_coords + (size_t)b * (S_TOT / 2) + z * (S_SUB / 2);
    const float4* __restrict__ sv4 =
        (const float4*)station_values + (size_t)b * (S_TOT / 4) + z * (S_SUB / 4);

    const int tid = blockIdx.x * BLOCK + threadIdx.x;
    const float4* __restrict__ gp4 = (const float4*)grid_points + (size_t)b * (P / 2);
    const float4 ga = gp4[4 * tid + 0];
    const float4 gb = gp4[4 * tid + 1];
    const float4 gc = gp4[4 * tid + 2];
    const float4 gd = gp4[4 * tid + 3];
    const float gx0 = ga.x, gy0 = ga.y, gx1 = ga.z, gy1 = ga.w;
    const float gx2 = gb.x, gy2 = gb.y, gx3 = gb.z, gy3 = gb.w;
    const float gx4 = gc.x, gy4 = gc.y, gx5 = gc.z, gy5 = gc.w;
    const float gx6 = gd.x, gy6 = gd.y, gx7 = gd.z, gy7 = gd.w;

    float ws0 = 0.0f, vs0 = 0.0f, ws1 = 0.0f, vs1 = 0.0f;
    float ws2 = 0.0f, vs2 = 0.0f, ws3 = 0.0f, vs3 = 0.0f;
    float ws4 = 0.0f, vs4 = 0.0f, ws5 = 0.0f, vs5 = 0.0f;
    float ws6 = 0.0f, vs6 = 0.0f, ws7 = 0.0f, vs7 = 0.0f;

#pragma unroll 4
    for (int k = 0; k < S_SUB / 4; ++k) {
        const float4 c0 = sc4[2 * k + 0];
        const float4 c1 = sc4[2 * k + 1];
        const float4 vv = sv4[k];
        quad_sm(gx0, gy0, ws0, vs0, c0, c1, vv);
        quad_sm(gx1, gy1, ws1, vs1, c0, c1, vv);
        quad_sm(gx2, gy2, ws2, vs2, c0, c1, vv);
        quad_sm(gx3, gy3, ws3, vs3, c0, c1, vv);
        quad_sm(gx4, gy4, ws4, vs4, c0, c1, vv);
        quad_sm(gx5, gy5, ws5, vs5, c0, c1, vv);
        quad_sm(gx6, gy6, ws6, vs6, c0, c1, vv);
        quad_sm(gx7, gy7, ws7, vs7, c0, c1, vv);
    }

    float4* __restrict__ pb4 = (float4*)(partial + ((size_t)(z * 2 + b)) * P);
    pb4[4 * tid + 0] = make_float4(ws0, vs0, ws1, vs1);
    pb4[4 * tid + 1] = make_float4(ws2, vs2, ws3, vs3);
    pb4[4 * tid + 2] = make_float4(ws4, vs4, ws5, vs5);
    pb4[4 * tid + 3] = make_float4(ws6, vs6, ws7, vs7);
}

// Combine: out = (sum_z vs) / (sum_z ws). 4 points/thread.
__global__ __launch_bounds__(256) void idw_combine(
    const float2* __restrict__ partial, float* __restrict__ out, int P) {
    const int gid = blockIdx.x * 256 + threadIdx.x;
    const int pp0 = gid * 4;              // flat point index over (B, P)
    const int b = pp0 >> 17;              // P = 131072 = 2^17
    const int p0 = pp0 & (131072 - 1);

    float wa = 0.f, va = 0.f, wb = 0.f, vb = 0.f;
    float wc = 0.f, vc = 0.f, wd = 0.f, vd = 0.f;
#pragma unroll
    for (int z = 0; z < NSPLIT; ++z) {
        const float4* __restrict__ src =
            (const float4*)(partial + ((size_t)(z * 2 + b)) * P);
        const float4 lo = src[p0 / 2 + 0];   // pts p0, p0+1
        const float4 hi = src[p0 / 2 + 1];   // pts p0+2, p0+3
        wa += lo.x; va += lo.y; wb += lo.z; vb += lo.w;
        wc += hi.x; vc += hi.y; wd += hi.z; vd += hi.w;
    }
    ((float4*)out)[((size_t)b * P + p0) / 4] =
        make_float4(va / wa, vb / wb, vc / wc, vd / wd);
}

// Fallback (ws too small; never expected): R12 single-kernel path.
__global__ __launch_bounds__(BLOCK) void idw_single(
    const float* __restrict__ station_coords, const float* __restrict__ station_values,
    const float* __restrict__ grid_points, float* __restrict__ out, int P, int S) {
    __shared__ float st[S_TOT * 3];
    const int b = blockIdx.y;
    const float2* __restrict__ sc2 = (const float2*)station_coords + (size_t)b * S;
    const float* __restrict__ svb = station_values + (size_t)b * S;
    for (int i = threadIdx.x; i < S; i += BLOCK) {
        const float2 c = sc2[i];
        st[3 * i + 0] = c.x; st[3 * i + 1] = c.y; st[3 * i + 2] = svb[i];
    }
    __syncthreads();
    const int tid = blockIdx.x * BLOCK + threadIdx.x;
    const float4* __restrict__ gp4 = (const float4*)grid_points + (size_t)b * (P / 2);
    const float4 ga = gp4[2 * tid + 0];
    const float4 gb = gp4[2 * tid + 1];
    float ws0 = 0, vs0 = 0, ws1 = 0, vs1 = 0, ws2 = 0, vs2 = 0, ws3 = 0, vs3 = 0;
    const float4* __restrict__ st4 = (const float4*)st;
    constexpr float EPS = 1.1920928955078125e-07f;
    constexpr float EPS2 = EPS * EPS;
#pragma unroll 4
    for (int k = 0; k < S_TOT / 4; ++k) {
        const float4 f0 = st4[3 * k + 0];
        const float4 f1 = st4[3 * k + 1];
        const float4 f2 = st4[3 * k + 2];
        // layout f0 = Ax Ay Av Bx | f1 = By Bv Cx Cy | f2 = Cv Dx Dy Dv
        auto q = [&](float gx, float gy, float& ws, float& vs) {
            const float dxa = gx - f0.x, dya = gy - f0.y;
            const float a = fmaf(dxa, dxa, fmaf(dya, dya, EPS2));
            const float dxb = gx - f0.w, dyb = gy - f1.x;
            const float bq = fmaf(dxb, dxb, fmaf(dyb, dyb, EPS2));
            const float dxc = gx - f1.z, dyc = gy - f1.w;
            const float c = fmaf(dxc, dxc, fmaf(dyc, dyc, EPS2));
            const float dxd = gx - f2.y, dyd = gy - f2.z;
            const float d = fmaf(dxd, dxd, fmaf(dyd, dyd, EPS2));
            const float pab = a * bq, pcd = c * d;
            const float sab = a + bq, scd = c + d;
            const float nab = fmaf(f1.y, a, f0.z * bq);
            const float ncd = fmaf(f2.w, c, f2.x * d);
            const float r = __builtin_amdgcn_rcpf(pab * pcd);
            ws = fmaf(fmaf(sab, pcd, scd * pab), r, ws);
            vs = fmaf(fmaf(nab, pcd, ncd * pab), r, vs);
        };
        q(ga.x, ga.y, ws0, vs0);
        q(ga.z, ga.w, ws1, vs1);
        q(gb.x, gb.y, ws2, vs2);
        q(gb.z, gb.w, ws3, vs3);
    }
    ((float4*)out)[(size_t)b * (P / 4) + tid] =
        make_float4(vs0 / ws0, vs1 / ws1, vs2 / ws2, vs3 / ws3);
}

extern "C" void kernel_launch(void* const* d_in, const int* in_sizes, int n_in,
                              void* d_out, int out_size, void* d_ws, size_t ws_size,
                              hipStream_t stream) {
    const float* station_coords = (const float*)d_in[0];
    const float* station_values = (const float*)d_in[1];
    const float* grid_points    = (const float*)d_in[2];
    float* out = (float*)d_out;

    const int B = 2;
    const int S = in_sizes[1] / B;   // 512
    const int P = out_size / B;      // 131072

    const size_t need = (size_t)NSPLIT * B * P * sizeof(float2);  // 4 MB
    if (ws_size >= need && d_ws != nullptr) {
        float2* partial = (float2*)d_ws;
        dim3 grid(P / (BLOCK * GPT), B, NSPLIT);  // 64 x 2 x 2 = 256 blocks
        idw_main<<<grid, dim3(BLOCK), 0, stream>>>(
            station_coords, station_values, grid_points, partial, P, S);
        dim3 cgrid((B * P) / (256 * 4));          // 256 blocks
        idw_combine<<<cgrid, dim3(256), 0, stream>>>(partial, out, P);
    } else {
        dim3 grid(P / (BLOCK * 4), B);
        idw_single<<<grid, dim3(BLOCK), 0, stream>>>(
            station_coords, station_values, grid_points, out, P, S);
    }
}

// Round 10
// 77.871 us; speedup vs baseline: 1.2010x; 1.2010x over previous
//
#include <hip/hip_runtime.h>

// IDW, POWER=2.0 -> w = 1/d2 (sqrt cancels). out = sum(w*v)/sum(w).
// B=2, P=131072, S=512.
// R15: SMEM dead twice (R8/R14, pre-committed branch). Revert to R10 (best,
//   78.6 = 40 fill + 26.2 kernel + 12.4 overhead) and pull the last
//   instruction-mix lever: TRANS. R9 calibration (+3 rcp/quad, -7 VALU ->
//   +8.6us) => wave64 v_rcp_f32 blocks issue ~18-28 cyc. At GPT=4 the
//   issue floor = 128 chunks x (4x62 + 4xt) ~ 17.1us@t=18 -> trans is ~25%
//   of the floor. Hierarchical combine: each merge level trades +3 plain
//   (+6cyc) for -1 trans (-18..28cyc). 4-way -> 16-way: per 16 stations/pt
//   124 plain + 4 trans -> 133 plain + 1 trans. Savings 36-66 cyc per
//   16-group/pt -> kernel -1.9..-3.5us. Floor -> ~15.1us.
//   Underflow: P16 = prod of 16 d2; typical ~1e-8, worst realistic ~5e-19
//   >> 1e-38 (consecutive stations are spatially random). Safe.
//   Structure otherwise EXACTLY R10: GPT=4, 256 blocks (1/CU), LDS packed
//   {x,y,v}, manual double-buffer over 16-station pairs (12 float4),
//   hand-unrolled x2 so rotation is register renaming (zero v_mov).
//   __launch_bounds__(256,1) funds ~140 VGPR at 1 block/CU.
//   Pre-committed: neutral (+-1us) => mix is floor'd, gap is structural
//   (40 + 12.4 + ~17 issue floor ~= 70us hard floor) -> declare ROOFLINE.
// EPS2 stays folded in each d2 fma chain (exact at d2==0, like ref).

#define BLOCK 256
#define S_MAX 512
#define GPT 4

__global__ __launch_bounds__(BLOCK, 1) void idw_kernel(
    const float* __restrict__ station_coords,  // (B, S, 2)
    const float* __restrict__ station_values,  // (B, S)
    const float* __restrict__ grid_points,     // (B, P, 2)
    float* __restrict__ out,                   // (B, P)
    int P, int S) {

    __shared__ float st[S_MAX * 3];  // packed {x,y,v}, 12B/station

    const int b = blockIdx.y;
    const float2* __restrict__ sc2 = (const float2*)(station_coords) + (size_t)b * S;
    const float*  __restrict__ svb = station_values + (size_t)b * S;

    for (int i = threadIdx.x; i < S; i += BLOCK) {
        const float2 c = sc2[i];
        st[3 * i + 0] = c.x;
        st[3 * i + 1] = c.y;
        st[3 * i + 2] = svb[i];
    }
    __syncthreads();

    const int tid = blockIdx.x * BLOCK + threadIdx.x;
    const float4* __restrict__ gp4 = (const float4*)grid_points + (size_t)b * (P / 2);
    const float4 ga = gp4[2 * tid + 0];
    const float4 gb = gp4[2 * tid + 1];
    const float gx0 = ga.x, gy0 = ga.y, gx1 = ga.z, gy1 = ga.w;
    const float gx2 = gb.x, gy2 = gb.y, gx3 = gb.z, gy3 = gb.w;

    constexpr float EPS  = 1.1920928955078125e-07f;
    constexpr float EPS2 = EPS * EPS;

    float ws0 = 0.0f, vs0 = 0.0f, ws1 = 0.0f, vs1 = 0.0f;
    float ws2 = 0.0f, vs2 = 0.0f, ws3 = 0.0f, vs3 = 0.0f;

    const float4* __restrict__ st4 = (const float4*)st;

    // 4 stations A..D (f0,f1,f2; layout f0=Ax Ay Av Bx | f1=By Bv Cx Cy |
    // f2=Cv Dx Dy Dv) vs one point -> partial numerators + product, NO rcp.
    // 29 plain ops.
    auto half4 = [&](float gx, float gy,
                     const float4& f0, const float4& f1, const float4& f2,
                     float& Pq, float& Wq, float& Vq) {
        const float dxa = gx - f0.x, dya = gy - f0.y;
        const float a = fmaf(dxa, dxa, fmaf(dya, dya, EPS2));
        const float dxb = gx - f0.w, dyb = gy - f1.x;
        const float bq = fmaf(dxb, dxb, fmaf(dyb, dyb, EPS2));
        const float dxc = gx - f1.z, dyc = gy - f1.w;
        const float c = fmaf(dxc, dxc, fmaf(dyc, dyc, EPS2));
        const float dxd = gx - f2.y, dyd = gy - f2.z;
        const float d = fmaf(dxd, dxd, fmaf(dyd, dyd, EPS2));
        const float pab = a * bq, pcd = c * d;
        const float sab = a + bq, scd = c + d;
        const float nab = fmaf(f1.y, a, f0.z * bq);  // vB*a + vA*b
        const float ncd = fmaf(f2.w, c, f2.x * d);   // vD*c + vC*d
        Wq = fmaf(sab, pcd, scd * pab);
        Vq = fmaf(nab, pcd, ncd * pab);
        Pq = pab * pcd;
    };

    // 16 stations (12 float4) vs one point: 4 half4 + 3 merges + 1 rcp.
    // 133 plain + 1 trans.
    auto pair16 = [&](float gx, float gy, float& ws, float& vs,
                      const float4 (&f)[12]) {
        float P1, W1, V1, P2, W2, V2, P3, W3, V3, P4, W4, V4;
        half4(gx, gy, f[0], f[1], f[2], P1, W1, V1);
        half4(gx, gy, f[3], f[4], f[5], P2, W2, V2);
        half4(gx, gy, f[6], f[7], f[8], P3, W3, V3);
        half4(gx, gy, f[9], f[10], f[11], P4, W4, V4);
        // 8-way merges
        const float P12 = P1 * P2;
        const float W12 = fmaf(W1, P2, W2 * P1);
        const float V12 = fmaf(V1, P2, V2 * P1);
        const float P34 = P3 * P4;
        const float W34 = fmaf(W3, P4, W4 * P3);
        const float V34 = fmaf(V3, P4, V4 * P3);
        // 16-way merge + single rcp
        const float P16 = P12 * P34;
        const float W16 = fmaf(W12, P34, W34 * P12);
        const float V16 = fmaf(V12, P34, V34 * P12);
        const float r = __builtin_amdgcn_rcpf(P16);
        ws = fmaf(W16, r, ws);
        vs = fmaf(V16, r, vs);
    };

    auto do4pts = [&](const float4 (&f)[12]) {
        pair16(gx0, gy0, ws0, vs0, f);
        pair16(gx1, gy1, ws1, vs1, f);
        pair16(gx2, gy2, ws2, vs2, f);
        pair16(gx3, gy3, ws3, vs3, f);
    };

    // 32 pairs of 16 stations; double-buffered, hand-unrolled x2 so the
    // rotation is pure register renaming (no v_mov).
    float4 cb[12], nb[12];
#pragma unroll
    for (int i = 0; i < 12; ++i) cb[i] = st4[i];

    for (int j = 0; j < 15; ++j) {
#pragma unroll
        for (int i = 0; i < 12; ++i) nb[i] = st4[12 * (2 * j + 1) + i];
        do4pts(cb);   // pair 2j
#pragma unroll
        for (int i = 0; i < 12; ++i) cb[i] = st4[12 * (2 * j + 2) + i];
        do4pts(nb);   // pair 2j+1
    }
    // cb = pair 30; load pair 31 and finish.
#pragma unroll
    for (int i = 0; i < 12; ++i) nb[i] = st4[12 * 31 + i];
    do4pts(cb);
    do4pts(nb);

    const float4 res = make_float4(vs0 / ws0, vs1 / ws1, vs2 / ws2, vs3 / ws3);
    ((float4*)out)[(size_t)b * (P / 4) + tid] = res;
}

extern "C" void kernel_launch(void* const* d_in, const int* in_sizes, int n_in,
                              void* d_out, int out_size, void* d_ws, size_t ws_size,
                              hipStream_t stream) {
    const float* station_coords = (const float*)d_in[0];
    const float* station_values = (const float*)d_in[1];
    const float* grid_points    = (const float*)d_in[2];
    float* out = (float*)d_out;

    const int B = 2;
    const int S = in_sizes[1] / B;   // 512
    const int P = out_size / B;      // 131072

    dim3 grid(P / (BLOCK * GPT), B);  // 128 x 2 = 256 blocks, 1 per CU
    dim3 block(BLOCK);
    idw_kernel<<<grid, block, 0, stream>>>(station_coords, station_values,
                                           grid_points, out, P, S);
}